// Round 6
// baseline (530.788 us; speedup 1.0000x reference)
//
#include <hip/hip_runtime.h>

typedef __attribute__((ext_vector_type(8))) __bf16 bf16x8;
typedef __attribute__((ext_vector_type(4))) float f32x4;
typedef __attribute__((ext_vector_type(8))) unsigned short u16x8;

__device__ __forceinline__ float bf2f(unsigned short h) {
  union { unsigned int u; float f; } a; a.u = ((unsigned int)h) << 16; return a.f;
}
__device__ __forceinline__ unsigned short f2bf(float f) {
  union { float f; unsigned int u; } a; a.f = f;
  unsigned int u = a.u;
  u += 0x7fffu + ((u >> 16) & 1u);   // RNE
  return (unsigned short)(u >> 16);
}
// alias-safe 16B ops (memcpy → ds_read_b128 / global_load_dwordx4; no TBAA UB)
__device__ __forceinline__ bf16x8 ld_frag(const unsigned short* p) {
  bf16x8 r; __builtin_memcpy(&r, p, 16); return r;
}
__device__ __forceinline__ void cp16(unsigned short* dst, const unsigned short* src) {
  u16x8 t; __builtin_memcpy(&t, src, 16); __builtin_memcpy(dst, &t, 16);
}

// ---------------------------------------------------------------- transpose
// out[n][k] = bf16(in[k][n]); in fp32, dim x dim
__global__ __launch_bounds__(256) void transpose_kernel(
    const float* __restrict__ in, unsigned short* __restrict__ out, int dim)
{
  __shared__ unsigned short tile[64 * 65];
  const int t = threadIdx.x;
  const int n0 = blockIdx.x * 64, k0 = blockIdx.y * 64;
#pragma unroll
  for (int e = 0; e < 16; e++) {
    int idx = e * 256 + t;
    int i = idx >> 6, j = idx & 63;
    tile[i * 65 + j] = f2bf(in[(size_t)(k0 + i) * dim + n0 + j]);
  }
  __syncthreads();
#pragma unroll
  for (int e = 0; e < 16; e++) {
    int idx = e * 256 + t;
    int i = idx >> 6, j = idx & 63;
    out[(size_t)(n0 + i) * dim + k0 + j] = tile[j * 65 + i];
  }
}

// ---------------------------------------------------------------- GEMM (B^T)
// C[M,N] = A[M,K]*BT[N,K]^T + bias[N]; BT,C bf16; bias fp32; A fp32 if a_f32.
__global__ __launch_bounds__(256) void gemm_bt_kernel(
    const void* __restrict__ A,
    const unsigned short* __restrict__ BT,
    const float* __restrict__ bias,
    unsigned short* __restrict__ C,
    int M, int N, int K, int a_f32)
{
  __shared__ unsigned short As[128 * 32];
  __shared__ unsigned short Bs[128 * 32];
  const int tid  = threadIdx.x;
  const int wave = tid >> 6;
  const int lane = tid & 63;
  const int quad = lane >> 4;
  const int l16  = lane & 15;
  const int m0 = blockIdx.x * 128;
  const int n0 = blockIdx.y * 128;
  const int wm = (wave & 1) * 64;
  const int wn = (wave >> 1) * 64;

  const f32x4 fz = {0.0f, 0.0f, 0.0f, 0.0f};
  f32x4 acc[4][4];
#pragma unroll
  for (int i = 0; i < 4; i++)
#pragma unroll
    for (int j = 0; j < 4; j++) acc[i][j] = fz;

  const int srow0 = tid >> 2;        // 0..63
  const int scol  = (tid & 3) * 8;   // 0,8,16,24

  for (int k0 = 0; k0 < K; k0 += 32) {
#pragma unroll
    for (int i = 0; i < 2; i++) {
      int row = srow0 + i * 64;
      size_t aidx = (size_t)(m0 + row) * K + k0 + scol;
      if (a_f32) {
        float tf[8]; __builtin_memcpy(tf, &((const float*)A)[aidx], 32);
        unsigned short tu[8];
#pragma unroll
        for (int j = 0; j < 8; j++) tu[j] = f2bf(tf[j]);
        __builtin_memcpy(&As[row * 32 + scol], tu, 16);
      } else {
        cp16(&As[row * 32 + scol], &((const unsigned short*)A)[aidx]);
      }
      cp16(&Bs[row * 32 + scol], &BT[(size_t)(n0 + row) * K + k0 + scol]);
    }
    __syncthreads();
    bf16x8 afr[4], bfr[4];
#pragma unroll
    for (int mt = 0; mt < 4; mt++) afr[mt] = ld_frag(&As[(wm + mt * 16 + l16) * 32 + quad * 8]);
#pragma unroll
    for (int nt = 0; nt < 4; nt++) bfr[nt] = ld_frag(&Bs[(wn + nt * 16 + l16) * 32 + quad * 8]);
#pragma unroll
    for (int mt = 0; mt < 4; mt++)
#pragma unroll
      for (int nt = 0; nt < 4; nt++)
        acc[mt][nt] = __builtin_amdgcn_mfma_f32_16x16x32_bf16(afr[mt], bfr[nt], acc[mt][nt], 0, 0, 0);
    __syncthreads();
  }

#pragma unroll
  for (int nt = 0; nt < 4; nt++) {
    int col = n0 + wn + nt * 16 + l16;
    float bv = bias[col];
#pragma unroll
    for (int mt = 0; mt < 4; mt++) {
      int rowb = m0 + wm + mt * 16 + quad * 4;
#pragma unroll
      for (int r = 0; r < 4; r++)
        C[(size_t)(rowb + r) * N + col] = f2bf(acc[mt][nt][r] + bv);
    }
  }
}

// ---------------------------------------------------------------- V-proj GEMM with transposed output
// vt[((b*16+h)*64+dv) * 2048 + key] = (V @ Wv + bv)[b*2048+key][h*64+dv]
__global__ __launch_bounds__(256) void gemm_bt_vt_kernel(
    const float* __restrict__ A,
    const unsigned short* __restrict__ BT,
    const float* __restrict__ bias,
    unsigned short* __restrict__ vt)
{
  __shared__ unsigned short As[128 * 32];
  __shared__ unsigned short Bs[128 * 32];
  __shared__ unsigned short Ts[4][64 * 72];   // per-wave 64x64 transpose tile
  const int K = 1024;
  const int tid  = threadIdx.x;
  const int wave = tid >> 6;
  const int lane = tid & 63;
  const int quad = lane >> 4;
  const int l16  = lane & 15;
  const int m0 = blockIdx.x * 128;
  const int n0 = blockIdx.y * 128;
  const int wm = (wave & 1) * 64;
  const int wn = (wave >> 1) * 64;

  const f32x4 fz = {0.0f, 0.0f, 0.0f, 0.0f};
  f32x4 acc[4][4];
#pragma unroll
  for (int i = 0; i < 4; i++)
#pragma unroll
    for (int j = 0; j < 4; j++) acc[i][j] = fz;

  const int srow0 = tid >> 2;
  const int scol  = (tid & 3) * 8;

  for (int k0 = 0; k0 < K; k0 += 32) {
#pragma unroll
    for (int i = 0; i < 2; i++) {
      int row = srow0 + i * 64;
      size_t aidx = (size_t)(m0 + row) * K + k0 + scol;
      float tf[8]; __builtin_memcpy(tf, &A[aidx], 32);
      unsigned short tu[8];
#pragma unroll
      for (int j = 0; j < 8; j++) tu[j] = f2bf(tf[j]);
      __builtin_memcpy(&As[row * 32 + scol], tu, 16);
      cp16(&Bs[row * 32 + scol], &BT[(size_t)(n0 + row) * K + k0 + scol]);
    }
    __syncthreads();
    bf16x8 afr[4], bfr[4];
#pragma unroll
    for (int mt = 0; mt < 4; mt++) afr[mt] = ld_frag(&As[(wm + mt * 16 + l16) * 32 + quad * 8]);
#pragma unroll
    for (int nt = 0; nt < 4; nt++) bfr[nt] = ld_frag(&Bs[(wn + nt * 16 + l16) * 32 + quad * 8]);
#pragma unroll
    for (int mt = 0; mt < 4; mt++)
#pragma unroll
      for (int nt = 0; nt < 4; nt++)
        acc[mt][nt] = __builtin_amdgcn_mfma_f32_16x16x32_bf16(afr[mt], bfr[nt], acc[mt][nt], 0, 0, 0);
    __syncthreads();
  }

#pragma unroll
  for (int nt = 0; nt < 4; nt++) {
    float bv = bias[n0 + wn + nt * 16 + l16];
#pragma unroll
    for (int mt = 0; mt < 4; mt++)
#pragma unroll
      for (int r = 0; r < 4; r++)
        Ts[wave][(nt * 16 + l16) * 72 + mt * 16 + quad * 4 + r] = f2bf(acc[mt][nt][r] + bv);
  }
  {
    const int R0 = m0 + wm;
    const int b  = R0 >> 11;
    const int key0 = R0 & 2047;
    const int col = n0 + wn + lane;
    const int h  = col >> 6, dv = col & 63;
    const size_t vtrow = ((size_t)(b * 16 + h)) * 64 + dv;
#pragma unroll
    for (int jb = 0; jb < 8; jb++)
      cp16((unsigned short*)&vt[vtrow * 2048 + key0 + jb * 8],
           &Ts[wave][lane * 72 + jb * 8]);
  }
}

// ---------------------------------------------------------------- attention
// Block = 256 threads = 4 waves, one block per (bh, q-group). Wave w handles
// keys [w*512, w*512+512) (4 tiles of 128), barrier-free; then one barrier
// and an LDS exp-weighted combine (flash-decoding within the block).
// bh = bid & 63 keeps the (b,h) K/V slice pinned to one XCD's L2.
__global__ __launch_bounds__(256, 5) void attn_kernel(
    const unsigned short* __restrict__ qp,   // [B*512, 1024] bf16
    const unsigned short* __restrict__ kp,   // [B*2048, 1024] bf16
    const unsigned short* __restrict__ vt,   // [B*16*64, 2048] bf16 (dv-major)
    const int* __restrict__ mask,            // [B, 2048]
    unsigned short* __restrict__ attn)       // [B*512, 1024] bf16
{
  __shared__ unsigned short Ps[4][16 * 136]; // per-wave P round-trip
  __shared__ unsigned short Opart[4][16 * 64]; // per-wave unnormalized O (bf16)
  __shared__ float Mpart[4][16], Lpart[4][16];

  const int tid  = threadIdx.x;
  const int wave = tid >> 6;
  const int lane = tid & 63;
  const int quad = lane >> 4;
  const int l16  = lane & 15;
  const int bid  = blockIdx.x;
  const int bh = bid & 63;       // XCD = bid%8 = bh%8
  const int qg = bid >> 6;       // q-group 0..31
  const int b = bh >> 4, h = bh & 15;

  // Q A-fragments (row = l16), loaded once (4x redundant across waves, L2-hit)
  bf16x8 aq[2];
  {
    const size_t qbase = ((size_t)(b * 512 + qg * 16 + l16)) * 1024 + h * 64;
#pragma unroll
    for (int kc = 0; kc < 2; kc++)
      aq[kc] = ld_frag(&qp[qbase + kc * 32 + quad * 8]);
  }

  const f32x4 fz = {0.0f, 0.0f, 0.0f, 0.0f};
  float m_i[4], l_i[4];
  f32x4 O[4];
#pragma unroll
  for (int r = 0; r < 4; r++) { m_i[r] = -1e30f; l_i[r] = 0.0f; }
#pragma unroll
  for (int d = 0; d < 4; d++) O[d] = fz;

  const size_t kbase = ((size_t)(b * 2048)) * 1024 + h * 64;
  const size_t vbase = ((size_t)(bh * 64)) * 2048;

  for (int it = 0; it < 4; it++) {           // this wave's 4 tiles of 128 keys
    const int kt = wave * 4 + it;
    // ---- S = Q K^T (16 x 128)
    f32x4 s[8];
#pragma unroll
    for (int nt = 0; nt < 8; nt++) s[nt] = fz;
#pragma unroll
    for (int nt = 0; nt < 8; nt++) {
      const size_t krow = kbase + ((size_t)(kt * 128 + nt * 16 + l16)) * 1024;
#pragma unroll
      for (int kc = 0; kc < 2; kc++) {
        bf16x8 bk = ld_frag(&kp[krow + kc * 32 + quad * 8]);
        s[nt] = __builtin_amdgcn_mfma_f32_16x16x32_bf16(aq[kc], bk, s[nt], 0, 0, 0);
      }
    }
    // ---- mask + scale
    bool okm[8];
#pragma unroll
    for (int nt = 0; nt < 8; nt++) {
      okm[nt] = (mask[b * 2048 + kt * 128 + nt * 16 + l16] != 0);
#pragma unroll
      for (int r = 0; r < 4; r++)
        s[nt][r] = okm[nt] ? s[nt][r] * 0.125f : -1e30f;
    }
    // ---- online softmax
    float mnew[4];
#pragma unroll
    for (int r = 0; r < 4; r++) {
      float mx = s[0][r];
#pragma unroll
      for (int nt = 1; nt < 8; nt++) mx = fmaxf(mx, s[nt][r]);
      mnew[r] = mx;
    }
#pragma unroll
    for (int off = 1; off < 16; off <<= 1)
#pragma unroll
      for (int r = 0; r < 4; r++) mnew[r] = fmaxf(mnew[r], __shfl_xor(mnew[r], off));
#pragma unroll
    for (int r = 0; r < 4; r++) mnew[r] = fmaxf(mnew[r], m_i[r]);

    float alpha[4], rs[4];
#pragma unroll
    for (int r = 0; r < 4; r++) {
      alpha[r] = __expf(m_i[r] - mnew[r]);
      m_i[r] = mnew[r];
      rs[r] = 0.0f;
    }
#pragma unroll
    for (int nt = 0; nt < 8; nt++)
#pragma unroll
      for (int r = 0; r < 4; r++) {
        float p = okm[nt] ? __expf(s[nt][r] - mnew[r]) : 0.0f;
        rs[r] += p;
        Ps[wave][(quad * 4 + r) * 136 + nt * 16 + l16] = f2bf(p);
      }
#pragma unroll
    for (int off = 1; off < 16; off <<= 1)
#pragma unroll
      for (int r = 0; r < 4; r++) rs[r] += __shfl_xor(rs[r], off);
#pragma unroll
    for (int r = 0; r < 4; r++) l_i[r] = l_i[r] * alpha[r] + rs[r];
#pragma unroll
    for (int d = 0; d < 4; d++)
#pragma unroll
      for (int r = 0; r < 4; r++) O[d][r] = O[d][r] * alpha[r];

    // ---- O += P V  (P A-frags from wave-private LDS; V B-frags direct global)
    bf16x8 ap[4];
#pragma unroll
    for (int kc = 0; kc < 4; kc++)
      ap[kc] = ld_frag(&Ps[wave][l16 * 136 + kc * 32 + quad * 8]);
#pragma unroll
    for (int dvt = 0; dvt < 4; dvt++) {
      const size_t vrow = vbase + ((size_t)(dvt * 16 + l16)) * 2048 + kt * 128;
#pragma unroll
      for (int kc = 0; kc < 4; kc++) {
        bf16x8 bv = ld_frag(&vt[vrow + kc * 32 + quad * 8]);
        O[dvt] = __builtin_amdgcn_mfma_f32_16x16x32_bf16(ap[kc], bv, O[dvt], 0, 0, 0);
      }
    }
  }

  // ---- post partials and combine across the 4 key-chunks
#pragma unroll
  for (int dvt = 0; dvt < 4; dvt++)
#pragma unroll
    for (int r = 0; r < 4; r++)
      Opart[wave][(quad * 4 + r) * 64 + dvt * 16 + l16] = f2bf(O[dvt][r]);
  if (l16 == 0) {
#pragma unroll
    for (int r = 0; r < 4; r++) {
      Mpart[wave][quad * 4 + r] = m_i[r];
      Lpart[wave][quad * 4 + r] = l_i[r];
    }
  }
  __syncthreads();

#pragma unroll
  for (int r = 0; r < 4; r++) {
    const int row = quad * 4 + r;
    float mw[4], msx = -1e30f;
#pragma unroll
    for (int w = 0; w < 4; w++) { mw[w] = Mpart[w][row]; msx = fmaxf(msx, mw[w]); }
    float lsum = 0.0f, wt[4];
#pragma unroll
    for (int w = 0; w < 4; w++) { wt[w] = __expf(mw[w] - msx); lsum += wt[w] * Lpart[w][row]; }
    float inv = (lsum > 0.0f) ? (1.0f / lsum) : 0.0f;
    // this wave stores the dv-slice dvt == wave
    float of = 0.0f;
#pragma unroll
    for (int w = 0; w < 4; w++)
      of += wt[w] * bf2f(Opart[w][row * 64 + wave * 16 + l16]);
    const int grow = b * 512 + qg * 16 + row;
    attn[(size_t)grow * 1024 + h * 64 + wave * 16 + l16] = f2bf(of * inv);
  }
}

// ---------------------------------------------------------------- layernorm
// out(fp32) = LN(x + resid) * gamma + beta; x bf16 ws; resid/gamma/beta fp32.
__global__ __launch_bounds__(256) void ln_kernel(
    const unsigned short* __restrict__ x,
    const float* __restrict__ resid,
    const float* __restrict__ gamma,
    const float* __restrict__ beta,
    float* __restrict__ out)
{
  const int row = blockIdx.x;
  const int t = threadIdx.x;
  const int wave = t >> 6, lane = t & 63;
  __shared__ float red[8];
  float v[4];
  float s1 = 0.0f, s2 = 0.0f;
#pragma unroll
  for (int i = 0; i < 4; i++) {
    int e = t + i * 256;
    float val = bf2f(x[(size_t)row * 1024 + e]) + resid[(size_t)row * 1024 + e];
    v[i] = val; s1 += val; s2 += val * val;
  }
#pragma unroll
  for (int off = 1; off < 64; off <<= 1) { s1 += __shfl_xor(s1, off); s2 += __shfl_xor(s2, off); }
  if (lane == 0) { red[wave] = s1; red[4 + wave] = s2; }
  __syncthreads();
  s1 = red[0] + red[1] + red[2] + red[3];
  s2 = red[4] + red[5] + red[6] + red[7];
  float mu  = s1 * (1.0f / 1024.0f);
  float var = s2 * (1.0f / 1024.0f) - mu * mu;
  float rstd = rsqrtf(var + 1e-5f);
#pragma unroll
  for (int i = 0; i < 4; i++) {
    int e = t + i * 256;
    out[(size_t)row * 1024 + e] = (v[i] - mu) * rstd * gamma[e] + beta[e];
  }
}

// ---------------------------------------------------------------- launch
extern "C" void kernel_launch(void* const* d_in, const int* in_sizes, int n_in,
                              void* d_out, int out_size, void* d_ws, size_t ws_size,
                              hipStream_t stream) {
  (void)out_size; (void)ws_size;
  const float* Q = (const float*)d_in[0];
  const float* K = (const float*)d_in[1];
  const float* V = (const float*)d_in[2];

  int ix = 3;
  if (ix < n_in && in_sizes[ix] == 1) ix++;   // skip node_num scalar if passed
  const int* mask  = (const int*)d_in[ix++];
  const float* Wq = (const float*)d_in[ix++]; const float* bq = (const float*)d_in[ix++];
  const float* Wk = (const float*)d_in[ix++]; const float* bk = (const float*)d_in[ix++];
  const float* Wv = (const float*)d_in[ix++]; const float* bv = (const float*)d_in[ix++];
  const float* Wo = (const float*)d_in[ix++]; const float* bo = (const float*)d_in[ix++];
  const float* gm = (const float*)d_in[ix++]; const float* bt = (const float*)d_in[ix++];

  // ws layout (42 MB; stream order serializes reuse)
  char* ws = (char*)d_ws;
  unsigned short* WT = (unsigned short*)(ws);                    // 2 MB, reused 4x
  unsigned short* qp = (unsigned short*)(ws + (2ull  << 20));    // 4 MB (reused as op)
  unsigned short* kp = (unsigned short*)(ws + (6ull  << 20));    // 16 MB
  unsigned short* vt = (unsigned short*)(ws + (22ull << 20));    // 16 MB (transposed V-proj)
  unsigned short* at = (unsigned short*)(ws + (38ull << 20));    // 4 MB
  unsigned short* op = qp;   // alias: qp dead after attn

  dim3 blk(256);
  transpose_kernel<<<dim3(16, 16), blk, 0, stream>>>(Wq, WT, 1024);
  gemm_bt_kernel<<<dim3(16, 8), blk, 0, stream>>>(Q, WT, bq, qp, 2048, 1024, 1024, 1);
  transpose_kernel<<<dim3(16, 16), blk, 0, stream>>>(Wk, WT, 1024);
  gemm_bt_kernel<<<dim3(64, 8), blk, 0, stream>>>(K, WT, bk, kp, 8192, 1024, 1024, 1);
  transpose_kernel<<<dim3(16, 16), blk, 0, stream>>>(Wv, WT, 1024);
  gemm_bt_vt_kernel<<<dim3(64, 8), blk, 0, stream>>>(V, WT, bv, vt);

  attn_kernel<<<dim3(2048), blk, 0, stream>>>(qp, kp, vt, mask, at);

  transpose_kernel<<<dim3(16, 16), blk, 0, stream>>>(Wo, WT, 1024);
  gemm_bt_kernel<<<dim3(16, 8), blk, 0, stream>>>(at, WT, bo, op, 2048, 1024, 1024, 0);

  ln_kernel<<<dim3(2048), blk, 0, stream>>>(op, Q, gm, bt, (float*)d_out);
}

// Round 7
// 476.382 us; speedup vs baseline: 1.1142x; 1.1142x over previous
//
#include <hip/hip_runtime.h>

typedef __attribute__((ext_vector_type(8))) __bf16 bf16x8;
typedef __attribute__((ext_vector_type(4))) float f32x4;
typedef __attribute__((ext_vector_type(8))) unsigned short u16x8;

__device__ __forceinline__ float bf2f(unsigned short h) {
  union { unsigned int u; float f; } a; a.u = ((unsigned int)h) << 16; return a.f;
}
__device__ __forceinline__ unsigned short f2bf(float f) {
  union { float f; unsigned int u; } a; a.f = f;
  unsigned int u = a.u;
  u += 0x7fffu + ((u >> 16) & 1u);   // RNE
  return (unsigned short)(u >> 16);
}
// alias-safe 16B ops (memcpy → ds_read_b128 / global_load_dwordx4; no TBAA UB)
__device__ __forceinline__ bf16x8 ld_frag(const unsigned short* p) {
  bf16x8 r; __builtin_memcpy(&r, p, 16); return r;
}
__device__ __forceinline__ void cp16(unsigned short* dst, const unsigned short* src) {
  u16x8 t; __builtin_memcpy(&t, src, 16); __builtin_memcpy(dst, &t, 16);
}

// ---------------------------------------------------------------- transpose
// out[n][k] = bf16(in[k][n]); in fp32, dim x dim
__global__ __launch_bounds__(256) void transpose_kernel(
    const float* __restrict__ in, unsigned short* __restrict__ out, int dim)
{
  __shared__ unsigned short tile[64 * 65];
  const int t = threadIdx.x;
  const int n0 = blockIdx.x * 64, k0 = blockIdx.y * 64;
#pragma unroll
  for (int e = 0; e < 16; e++) {
    int idx = e * 256 + t;
    int i = idx >> 6, j = idx & 63;
    tile[i * 65 + j] = f2bf(in[(size_t)(k0 + i) * dim + n0 + j]);
  }
  __syncthreads();
#pragma unroll
  for (int e = 0; e < 16; e++) {
    int idx = e * 256 + t;
    int i = idx >> 6, j = idx & 63;
    out[(size_t)(n0 + i) * dim + k0 + j] = tile[j * 65 + i];
  }
}

// ---------------------------------------------------------------- GEMM (B^T)
// C[M,N] = A[M,K]*BT[N,K]^T + bias[N]; BT,C bf16; bias fp32; A fp32 if a_f32.
__global__ __launch_bounds__(256) void gemm_bt_kernel(
    const void* __restrict__ A,
    const unsigned short* __restrict__ BT,
    const float* __restrict__ bias,
    unsigned short* __restrict__ C,
    int M, int N, int K, int a_f32)
{
  __shared__ unsigned short As[128 * 32];
  __shared__ unsigned short Bs[128 * 32];
  const int tid  = threadIdx.x;
  const int wave = tid >> 6;
  const int lane = tid & 63;
  const int quad = lane >> 4;
  const int l16  = lane & 15;
  const int m0 = blockIdx.x * 128;
  const int n0 = blockIdx.y * 128;
  const int wm = (wave & 1) * 64;
  const int wn = (wave >> 1) * 64;

  const f32x4 fz = {0.0f, 0.0f, 0.0f, 0.0f};
  f32x4 acc[4][4];
#pragma unroll
  for (int i = 0; i < 4; i++)
#pragma unroll
    for (int j = 0; j < 4; j++) acc[i][j] = fz;

  const int srow0 = tid >> 2;        // 0..63
  const int scol  = (tid & 3) * 8;   // 0,8,16,24

  for (int k0 = 0; k0 < K; k0 += 32) {
#pragma unroll
    for (int i = 0; i < 2; i++) {
      int row = srow0 + i * 64;
      size_t aidx = (size_t)(m0 + row) * K + k0 + scol;
      if (a_f32) {
        float tf[8]; __builtin_memcpy(tf, &((const float*)A)[aidx], 32);
        unsigned short tu[8];
#pragma unroll
        for (int j = 0; j < 8; j++) tu[j] = f2bf(tf[j]);
        __builtin_memcpy(&As[row * 32 + scol], tu, 16);
      } else {
        cp16(&As[row * 32 + scol], &((const unsigned short*)A)[aidx]);
      }
      cp16(&Bs[row * 32 + scol], &BT[(size_t)(n0 + row) * K + k0 + scol]);
    }
    __syncthreads();
    bf16x8 afr[4], bfr[4];
#pragma unroll
    for (int mt = 0; mt < 4; mt++) afr[mt] = ld_frag(&As[(wm + mt * 16 + l16) * 32 + quad * 8]);
#pragma unroll
    for (int nt = 0; nt < 4; nt++) bfr[nt] = ld_frag(&Bs[(wn + nt * 16 + l16) * 32 + quad * 8]);
#pragma unroll
    for (int mt = 0; mt < 4; mt++)
#pragma unroll
      for (int nt = 0; nt < 4; nt++)
        acc[mt][nt] = __builtin_amdgcn_mfma_f32_16x16x32_bf16(afr[mt], bfr[nt], acc[mt][nt], 0, 0, 0);
    __syncthreads();
  }

#pragma unroll
  for (int nt = 0; nt < 4; nt++) {
    int col = n0 + wn + nt * 16 + l16;
    float bv = bias[col];
#pragma unroll
    for (int mt = 0; mt < 4; mt++) {
      int rowb = m0 + wm + mt * 16 + quad * 4;
#pragma unroll
      for (int r = 0; r < 4; r++)
        C[(size_t)(rowb + r) * N + col] = f2bf(acc[mt][nt][r] + bv);
    }
  }
}

// ---------------------------------------------------------------- V-proj GEMM with transposed output
// vt[((b*16+h)*64+dv) * 2048 + key] = (V @ Wv + bv)[b*2048+key][h*64+dv]
__global__ __launch_bounds__(256) void gemm_bt_vt_kernel(
    const float* __restrict__ A,
    const unsigned short* __restrict__ BT,
    const float* __restrict__ bias,
    unsigned short* __restrict__ vt)
{
  __shared__ unsigned short As[128 * 32];
  __shared__ unsigned short Bs[128 * 32];
  __shared__ unsigned short Ts[4][64 * 72];   // per-wave 64x64 transpose tile
  const int K = 1024;
  const int tid  = threadIdx.x;
  const int wave = tid >> 6;
  const int lane = tid & 63;
  const int quad = lane >> 4;
  const int l16  = lane & 15;
  const int m0 = blockIdx.x * 128;
  const int n0 = blockIdx.y * 128;
  const int wm = (wave & 1) * 64;
  const int wn = (wave >> 1) * 64;

  const f32x4 fz = {0.0f, 0.0f, 0.0f, 0.0f};
  f32x4 acc[4][4];
#pragma unroll
  for (int i = 0; i < 4; i++)
#pragma unroll
    for (int j = 0; j < 4; j++) acc[i][j] = fz;

  const int srow0 = tid >> 2;
  const int scol  = (tid & 3) * 8;

  for (int k0 = 0; k0 < K; k0 += 32) {
#pragma unroll
    for (int i = 0; i < 2; i++) {
      int row = srow0 + i * 64;
      size_t aidx = (size_t)(m0 + row) * K + k0 + scol;
      float tf[8]; __builtin_memcpy(tf, &A[aidx], 32);
      unsigned short tu[8];
#pragma unroll
      for (int j = 0; j < 8; j++) tu[j] = f2bf(tf[j]);
      __builtin_memcpy(&As[row * 32 + scol], tu, 16);
      cp16(&Bs[row * 32 + scol], &BT[(size_t)(n0 + row) * K + k0 + scol]);
    }
    __syncthreads();
    bf16x8 afr[4], bfr[4];
#pragma unroll
    for (int mt = 0; mt < 4; mt++) afr[mt] = ld_frag(&As[(wm + mt * 16 + l16) * 32 + quad * 8]);
#pragma unroll
    for (int nt = 0; nt < 4; nt++) bfr[nt] = ld_frag(&Bs[(wn + nt * 16 + l16) * 32 + quad * 8]);
#pragma unroll
    for (int mt = 0; mt < 4; mt++)
#pragma unroll
      for (int nt = 0; nt < 4; nt++)
        acc[mt][nt] = __builtin_amdgcn_mfma_f32_16x16x32_bf16(afr[mt], bfr[nt], acc[mt][nt], 0, 0, 0);
    __syncthreads();
  }

#pragma unroll
  for (int nt = 0; nt < 4; nt++) {
    float bv = bias[n0 + wn + nt * 16 + l16];
#pragma unroll
    for (int mt = 0; mt < 4; mt++)
#pragma unroll
      for (int r = 0; r < 4; r++)
        Ts[wave][(nt * 16 + l16) * 72 + mt * 16 + quad * 4 + r] = f2bf(acc[mt][nt][r] + bv);
  }
  {
    const int R0 = m0 + wm;
    const int b  = R0 >> 11;
    const int key0 = R0 & 2047;
    const int col = n0 + wn + lane;
    const int h  = col >> 6, dv = col & 63;
    const size_t vtrow = ((size_t)(b * 16 + h)) * 64 + dv;
#pragma unroll
    for (int jb = 0; jb < 8; jb++)
      cp16((unsigned short*)&vt[vtrow * 2048 + key0 + jb * 8],
           &Ts[wave][lane * 72 + jb * 8]);
  }
}

// ---------------------------------------------------------------- attention
// One WAVE (64-thread block) per 16 q-rows of one (b,h); grid 2048,
// bh = bid & 63 pins each (b,h)'s K/V slice to one XCD's L2 (R5 structure).
// Key change vs R5: BATCHED loads. All 16 K-fragments are loaded into
// registers before the S-MFMAs (one waitcnt instead of ~16), all 16
// V-fragments are issued before the softmax (latency hidden under VALU),
// masks batched too. __launch_bounds__(64,2) caps VGPR at 256 (grid gives
// exactly 2 waves/SIMD).
__global__ __launch_bounds__(64, 2) void attn_kernel(
    const unsigned short* __restrict__ qp,   // [B*512, 1024] bf16
    const unsigned short* __restrict__ kp,   // [B*2048, 1024] bf16
    const unsigned short* __restrict__ vt,   // [B*16*64, 2048] bf16 (dv-major)
    const int* __restrict__ mask,            // [B, 2048]
    unsigned short* __restrict__ attn)       // [B*512, 1024] bf16
{
  __shared__ unsigned short Ps[16 * 136];    // P C->A layout round trip

  const int lane = threadIdx.x;
  const int quad = lane >> 4;
  const int l16  = lane & 15;
  const int bid  = blockIdx.x;
  const int bh = bid & 63;       // XCD = bid%8 = bh%8
  const int qg = bid >> 6;       // q-group 0..31
  const int b = bh >> 4, h = bh & 15;

  // Q A-fragments (row = l16), loaded once
  bf16x8 aq[2];
  {
    const size_t qbase = ((size_t)(b * 512 + qg * 16 + l16)) * 1024 + h * 64;
#pragma unroll
    for (int kc = 0; kc < 2; kc++)
      aq[kc] = ld_frag(&qp[qbase + kc * 32 + quad * 8]);
  }

  const f32x4 fz = {0.0f, 0.0f, 0.0f, 0.0f};
  float m_i[4], l_i[4];
  f32x4 O[4];
#pragma unroll
  for (int r = 0; r < 4; r++) { m_i[r] = -1e30f; l_i[r] = 0.0f; }
#pragma unroll
  for (int d = 0; d < 4; d++) O[d] = fz;

  const size_t kbase = ((size_t)(b * 2048)) * 1024 + h * 64;
  const size_t vbase = ((size_t)(bh * 64)) * 2048;

  for (int kt = 0; kt < 16; kt++) {          // 128 keys per tile
    // ---- BATCH: all 16 K-fragments + 8 mask words
    bf16x8 bk[8][2];
    int mk[8];
#pragma unroll
    for (int nt = 0; nt < 8; nt++) {
      const size_t krow = kbase + ((size_t)(kt * 128 + nt * 16 + l16)) * 1024;
#pragma unroll
      for (int kc = 0; kc < 2; kc++)
        bk[nt][kc] = ld_frag(&kp[krow + kc * 32 + quad * 8]);
      mk[nt] = mask[b * 2048 + kt * 128 + nt * 16 + l16];
    }
    // ---- S = Q K^T (16 x 128)
    f32x4 s[8];
#pragma unroll
    for (int nt = 0; nt < 8; nt++) s[nt] = fz;
#pragma unroll
    for (int nt = 0; nt < 8; nt++)
#pragma unroll
      for (int kc = 0; kc < 2; kc++)
        s[nt] = __builtin_amdgcn_mfma_f32_16x16x32_bf16(aq[kc], bk[nt][kc], s[nt], 0, 0, 0);

    // ---- BATCH: all 16 V-fragments (no dependency on softmax; in flight
    // while the VALU does max/exp/sum)
    bf16x8 bv[4][4];
#pragma unroll
    for (int dvt = 0; dvt < 4; dvt++) {
      const size_t vrow = vbase + ((size_t)(dvt * 16 + l16)) * 2048 + kt * 128;
#pragma unroll
      for (int kc = 0; kc < 4; kc++)
        bv[dvt][kc] = ld_frag(&vt[vrow + kc * 32 + quad * 8]);
    }

    // ---- mask + scale
    bool okm[8];
#pragma unroll
    for (int nt = 0; nt < 8; nt++) {
      okm[nt] = (mk[nt] != 0);
#pragma unroll
      for (int r = 0; r < 4; r++)
        s[nt][r] = okm[nt] ? s[nt][r] * 0.125f : -1e30f;
    }
    // ---- online softmax
    float mnew[4];
#pragma unroll
    for (int r = 0; r < 4; r++) {
      float mx = s[0][r];
#pragma unroll
      for (int nt = 1; nt < 8; nt++) mx = fmaxf(mx, s[nt][r]);
      mnew[r] = mx;
    }
#pragma unroll
    for (int off = 1; off < 16; off <<= 1)
#pragma unroll
      for (int r = 0; r < 4; r++) mnew[r] = fmaxf(mnew[r], __shfl_xor(mnew[r], off));
#pragma unroll
    for (int r = 0; r < 4; r++) mnew[r] = fmaxf(mnew[r], m_i[r]);

    float alpha[4], rs[4];
#pragma unroll
    for (int r = 0; r < 4; r++) {
      alpha[r] = __expf(m_i[r] - mnew[r]);
      m_i[r] = mnew[r];
      rs[r] = 0.0f;
    }
#pragma unroll
    for (int nt = 0; nt < 8; nt++)
#pragma unroll
      for (int r = 0; r < 4; r++) {
        float p = okm[nt] ? __expf(s[nt][r] - mnew[r]) : 0.0f;
        rs[r] += p;
        Ps[(quad * 4 + r) * 136 + nt * 16 + l16] = f2bf(p);
      }
#pragma unroll
    for (int off = 1; off < 16; off <<= 1)
#pragma unroll
      for (int r = 0; r < 4; r++) rs[r] += __shfl_xor(rs[r], off);
#pragma unroll
    for (int r = 0; r < 4; r++) l_i[r] = l_i[r] * alpha[r] + rs[r];
#pragma unroll
    for (int d = 0; d < 4; d++)
#pragma unroll
      for (int r = 0; r < 4; r++) O[d][r] = O[d][r] * alpha[r];

    // ---- O += P V  (P A-frags from wave-private LDS; V already in regs)
    bf16x8 ap[4];
#pragma unroll
    for (int kc = 0; kc < 4; kc++)
      ap[kc] = ld_frag(&Ps[l16 * 136 + kc * 32 + quad * 8]);
#pragma unroll
    for (int dvt = 0; dvt < 4; dvt++)
#pragma unroll
      for (int kc = 0; kc < 4; kc++)
        O[dvt] = __builtin_amdgcn_mfma_f32_16x16x32_bf16(ap[kc], bv[dvt][kc], O[dvt], 0, 0, 0);
  }

#pragma unroll
  for (int r = 0; r < 4; r++) {
    float linv = (l_i[r] > 0.0f) ? (1.0f / l_i[r]) : 0.0f;
    int row = b * 512 + qg * 16 + quad * 4 + r;
#pragma unroll
    for (int dvt = 0; dvt < 4; dvt++)
      attn[(size_t)row * 1024 + h * 64 + dvt * 16 + l16] = f2bf(O[dvt][r] * linv);
  }
}

// ---------------------------------------------------------------- layernorm
// out(fp32) = LN(x + resid) * gamma + beta; x bf16 ws; resid/gamma/beta fp32.
__global__ __launch_bounds__(256) void ln_kernel(
    const unsigned short* __restrict__ x,
    const float* __restrict__ resid,
    const float* __restrict__ gamma,
    const float* __restrict__ beta,
    float* __restrict__ out)
{
  const int row = blockIdx.x;
  const int t = threadIdx.x;
  const int wave = t >> 6, lane = t & 63;
  __shared__ float red[8];
  float v[4];
  float s1 = 0.0f, s2 = 0.0f;
#pragma unroll
  for (int i = 0; i < 4; i++) {
    int e = t + i * 256;
    float val = bf2f(x[(size_t)row * 1024 + e]) + resid[(size_t)row * 1024 + e];
    v[i] = val; s1 += val; s2 += val * val;
  }
#pragma unroll
  for (int off = 1; off < 64; off <<= 1) { s1 += __shfl_xor(s1, off); s2 += __shfl_xor(s2, off); }
  if (lane == 0) { red[wave] = s1; red[4 + wave] = s2; }
  __syncthreads();
  s1 = red[0] + red[1] + red[2] + red[3];
  s2 = red[4] + red[5] + red[6] + red[7];
  float mu  = s1 * (1.0f / 1024.0f);
  float var = s2 * (1.0f / 1024.0f) - mu * mu;
  float rstd = rsqrtf(var + 1e-5f);
#pragma unroll
  for (int i = 0; i < 4; i++) {
    int e = t + i * 256;
    out[(size_t)row * 1024 + e] = (v[i] - mu) * rstd * gamma[e] + beta[e];
  }
}

// ---------------------------------------------------------------- launch
extern "C" void kernel_launch(void* const* d_in, const int* in_sizes, int n_in,
                              void* d_out, int out_size, void* d_ws, size_t ws_size,
                              hipStream_t stream) {
  (void)out_size; (void)ws_size;
  const float* Q = (const float*)d_in[0];
  const float* K = (const float*)d_in[1];
  const float* V = (const float*)d_in[2];

  int ix = 3;
  if (ix < n_in && in_sizes[ix] == 1) ix++;   // skip node_num scalar if passed
  const int* mask  = (const int*)d_in[ix++];
  const float* Wq = (const float*)d_in[ix++]; const float* bq = (const float*)d_in[ix++];
  const float* Wk = (const float*)d_in[ix++]; const float* bk = (const float*)d_in[ix++];
  const float* Wv = (const float*)d_in[ix++]; const float* bv = (const float*)d_in[ix++];
  const float* Wo = (const float*)d_in[ix++]; const float* bo = (const float*)d_in[ix++];
  const float* gm = (const float*)d_in[ix++]; const float* bt = (const float*)d_in[ix++];

  // ws layout (42 MB; stream order serializes reuse)
  char* ws = (char*)d_ws;
  unsigned short* WT = (unsigned short*)(ws);                    // 2 MB, reused 4x
  unsigned short* qp = (unsigned short*)(ws + (2ull  << 20));    // 4 MB (reused as op)
  unsigned short* kp = (unsigned short*)(ws + (6ull  << 20));    // 16 MB
  unsigned short* vt = (unsigned short*)(ws + (22ull << 20));    // 16 MB (transposed V-proj)
  unsigned short* at = (unsigned short*)(ws + (38ull << 20));    // 4 MB
  unsigned short* op = qp;   // alias: qp dead after attn

  dim3 blk(256);
  transpose_kernel<<<dim3(16, 16), blk, 0, stream>>>(Wq, WT, 1024);
  gemm_bt_kernel<<<dim3(16, 8), blk, 0, stream>>>(Q, WT, bq, qp, 2048, 1024, 1024, 1);
  transpose_kernel<<<dim3(16, 16), blk, 0, stream>>>(Wk, WT, 1024);
  gemm_bt_kernel<<<dim3(64, 8), blk, 0, stream>>>(K, WT, bk, kp, 8192, 1024, 1024, 1);
  transpose_kernel<<<dim3(16, 16), blk, 0, stream>>>(Wv, WT, 1024);
  gemm_bt_vt_kernel<<<dim3(64, 8), blk, 0, stream>>>(V, WT, bv, vt);

  attn_kernel<<<dim3(2048), dim3(64), 0, stream>>>(qp, kp, vt, mask, at);

  transpose_kernel<<<dim3(16, 16), blk, 0, stream>>>(Wo, WT, 1024);
  gemm_bt_kernel<<<dim3(16, 8), blk, 0, stream>>>(at, WT, bo, op, 2048, 1024, 1024, 0);

  ln_kernel<<<dim3(2048), blk, 0, stream>>>(op, Q, gm, bt, (float*)d_out);
}

// Round 8
// 435.652 us; speedup vs baseline: 1.2184x; 1.0935x over previous
//
#include <hip/hip_runtime.h>

typedef __attribute__((ext_vector_type(8))) __bf16 bf16x8;
typedef __attribute__((ext_vector_type(4))) float f32x4;
typedef __attribute__((ext_vector_type(8))) unsigned short u16x8;

__device__ __forceinline__ float bf2f(unsigned short h) {
  union { unsigned int u; float f; } a; a.u = ((unsigned int)h) << 16; return a.f;
}
__device__ __forceinline__ unsigned short f2bf(float f) {
  union { float f; unsigned int u; } a; a.f = f;
  unsigned int u = a.u;
  u += 0x7fffu + ((u >> 16) & 1u);   // RNE
  return (unsigned short)(u >> 16);
}
// alias-safe 16B ops (memcpy → ds_read_b128 / global_load_dwordx4; no TBAA UB)
__device__ __forceinline__ bf16x8 ld_frag(const unsigned short* p) {
  bf16x8 r; __builtin_memcpy(&r, p, 16); return r;
}
__device__ __forceinline__ void cp16(unsigned short* dst, const unsigned short* src) {
  u16x8 t; __builtin_memcpy(&t, src, 16); __builtin_memcpy(dst, &t, 16);
}

// ---------------------------------------------------------------- fp32 -> bf16 bulk convert
__global__ __launch_bounds__(256) void cvt_kernel(
    const float* __restrict__ in, unsigned short* __restrict__ out, int n8)
{
  int i = blockIdx.x * 256 + threadIdx.x;
  if (i >= n8) return;
  float tf[8]; __builtin_memcpy(tf, &in[(size_t)i * 8], 32);
  unsigned short tu[8];
#pragma unroll
  for (int j = 0; j < 8; j++) tu[j] = f2bf(tf[j]);
  __builtin_memcpy(&out[(size_t)i * 8], tu, 16);
}

// ---------------------------------------------------------------- transpose (single, fp32 in)
__global__ __launch_bounds__(256) void transpose_kernel(
    const float* __restrict__ in, unsigned short* __restrict__ out, int dim)
{
  __shared__ unsigned short tile[64 * 65];
  const int t = threadIdx.x;
  const int n0 = blockIdx.x * 64, k0 = blockIdx.y * 64;
#pragma unroll
  for (int e = 0; e < 16; e++) {
    int idx = e * 256 + t;
    int i = idx >> 6, j = idx & 63;
    tile[i * 65 + j] = f2bf(in[(size_t)(k0 + i) * dim + n0 + j]);
  }
  __syncthreads();
#pragma unroll
  for (int e = 0; e < 16; e++) {
    int idx = e * 256 + t;
    int i = idx >> 6, j = idx & 63;
    out[(size_t)(n0 + i) * dim + k0 + j] = tile[j * 65 + i];
  }
}

// ---------------------------------------------------------------- fused 4-weight transpose
// z = blockIdx.z picks weight; out slot z is 1024x1024 bf16 at out + z*1048576.
__global__ __launch_bounds__(256) void transpose4_kernel(
    const float* __restrict__ w0, const float* __restrict__ w1,
    const float* __restrict__ w2, const float* __restrict__ w3,
    unsigned short* __restrict__ out)
{
  __shared__ unsigned short tile[64 * 65];
  const int z = blockIdx.z;
  const float* in = (z == 0) ? w0 : (z == 1) ? w1 : (z == 2) ? w2 : w3;
  unsigned short* o = out + (size_t)z * 1048576;
  const int dim = 1024;
  const int t = threadIdx.x;
  const int n0 = blockIdx.x * 64, k0 = blockIdx.y * 64;
#pragma unroll
  for (int e = 0; e < 16; e++) {
    int idx = e * 256 + t;
    int i = idx >> 6, j = idx & 63;
    tile[i * 65 + j] = f2bf(in[(size_t)(k0 + i) * dim + n0 + j]);
  }
  __syncthreads();
#pragma unroll
  for (int e = 0; e < 16; e++) {
    int idx = e * 256 + t;
    int i = idx >> 6, j = idx & 63;
    o[(size_t)(n0 + i) * dim + k0 + j] = tile[j * 65 + i];
  }
}

// ---------------------------------------------------------------- GEMM (B^T)
// C[M,N] = A[M,K]*BT[N,K]^T + bias[N]; BT,C bf16; bias fp32; A fp32 if a_f32.
__global__ __launch_bounds__(256) void gemm_bt_kernel(
    const void* __restrict__ A,
    const unsigned short* __restrict__ BT,
    const float* __restrict__ bias,
    unsigned short* __restrict__ C,
    int M, int N, int K, int a_f32)
{
  __shared__ unsigned short As[128 * 32];
  __shared__ unsigned short Bs[128 * 32];
  const int tid  = threadIdx.x;
  const int wave = tid >> 6;
  const int lane = tid & 63;
  const int quad = lane >> 4;
  const int l16  = lane & 15;
  const int m0 = blockIdx.x * 128;
  const int n0 = blockIdx.y * 128;
  const int wm = (wave & 1) * 64;
  const int wn = (wave >> 1) * 64;

  const f32x4 fz = {0.0f, 0.0f, 0.0f, 0.0f};
  f32x4 acc[4][4];
#pragma unroll
  for (int i = 0; i < 4; i++)
#pragma unroll
    for (int j = 0; j < 4; j++) acc[i][j] = fz;

  const int srow0 = tid >> 2;        // 0..63
  const int scol  = (tid & 3) * 8;   // 0,8,16,24

  for (int k0 = 0; k0 < K; k0 += 32) {
#pragma unroll
    for (int i = 0; i < 2; i++) {
      int row = srow0 + i * 64;
      size_t aidx = (size_t)(m0 + row) * K + k0 + scol;
      if (a_f32) {
        float tf[8]; __builtin_memcpy(tf, &((const float*)A)[aidx], 32);
        unsigned short tu[8];
#pragma unroll
        for (int j = 0; j < 8; j++) tu[j] = f2bf(tf[j]);
        __builtin_memcpy(&As[row * 32 + scol], tu, 16);
      } else {
        cp16(&As[row * 32 + scol], &((const unsigned short*)A)[aidx]);
      }
      cp16(&Bs[row * 32 + scol], &BT[(size_t)(n0 + row) * K + k0 + scol]);
    }
    __syncthreads();
    bf16x8 afr[4], bfr[4];
#pragma unroll
    for (int mt = 0; mt < 4; mt++) afr[mt] = ld_frag(&As[(wm + mt * 16 + l16) * 32 + quad * 8]);
#pragma unroll
    for (int nt = 0; nt < 4; nt++) bfr[nt] = ld_frag(&Bs[(wn + nt * 16 + l16) * 32 + quad * 8]);
#pragma unroll
    for (int mt = 0; mt < 4; mt++)
#pragma unroll
      for (int nt = 0; nt < 4; nt++)
        acc[mt][nt] = __builtin_amdgcn_mfma_f32_16x16x32_bf16(afr[mt], bfr[nt], acc[mt][nt], 0, 0, 0);
    __syncthreads();
  }

#pragma unroll
  for (int nt = 0; nt < 4; nt++) {
    int col = n0 + wn + nt * 16 + l16;
    float bv = bias[col];
#pragma unroll
    for (int mt = 0; mt < 4; mt++) {
      int rowb = m0 + wm + mt * 16 + quad * 4;
#pragma unroll
      for (int r = 0; r < 4; r++)
        C[(size_t)(rowb + r) * N + col] = f2bf(acc[mt][nt][r] + bv);
    }
  }
}

// ---------------------------------------------------------------- V-proj GEMM, transposed output
// vt[((b*16+h)*64+dv) * 2048 + key] = (V @ Wv + bv)[b*2048+key][h*64+dv]
__global__ __launch_bounds__(256) void gemm_bt_vt_kernel(
    const void* __restrict__ A,
    const unsigned short* __restrict__ BT,
    const float* __restrict__ bias,
    unsigned short* __restrict__ vt, int a_f32)
{
  __shared__ unsigned short As[128 * 32];
  __shared__ unsigned short Bs[128 * 32];
  __shared__ unsigned short Ts[4][64 * 72];   // per-wave 64x64 transpose tile
  const int K = 1024;
  const int tid  = threadIdx.x;
  const int wave = tid >> 6;
  const int lane = tid & 63;
  const int quad = lane >> 4;
  const int l16  = lane & 15;
  const int m0 = blockIdx.x * 128;
  const int n0 = blockIdx.y * 128;
  const int wm = (wave & 1) * 64;
  const int wn = (wave >> 1) * 64;

  const f32x4 fz = {0.0f, 0.0f, 0.0f, 0.0f};
  f32x4 acc[4][4];
#pragma unroll
  for (int i = 0; i < 4; i++)
#pragma unroll
    for (int j = 0; j < 4; j++) acc[i][j] = fz;

  const int srow0 = tid >> 2;
  const int scol  = (tid & 3) * 8;

  for (int k0 = 0; k0 < K; k0 += 32) {
#pragma unroll
    for (int i = 0; i < 2; i++) {
      int row = srow0 + i * 64;
      size_t aidx = (size_t)(m0 + row) * K + k0 + scol;
      if (a_f32) {
        float tf[8]; __builtin_memcpy(tf, &((const float*)A)[aidx], 32);
        unsigned short tu[8];
#pragma unroll
        for (int j = 0; j < 8; j++) tu[j] = f2bf(tf[j]);
        __builtin_memcpy(&As[row * 32 + scol], tu, 16);
      } else {
        cp16(&As[row * 32 + scol], &((const unsigned short*)A)[aidx]);
      }
      cp16(&Bs[row * 32 + scol], &BT[(size_t)(n0 + row) * K + k0 + scol]);
    }
    __syncthreads();
    bf16x8 afr[4], bfr[4];
#pragma unroll
    for (int mt = 0; mt < 4; mt++) afr[mt] = ld_frag(&As[(wm + mt * 16 + l16) * 32 + quad * 8]);
#pragma unroll
    for (int nt = 0; nt < 4; nt++) bfr[nt] = ld_frag(&Bs[(wn + nt * 16 + l16) * 32 + quad * 8]);
#pragma unroll
    for (int mt = 0; mt < 4; mt++)
#pragma unroll
      for (int nt = 0; nt < 4; nt++)
        acc[mt][nt] = __builtin_amdgcn_mfma_f32_16x16x32_bf16(afr[mt], bfr[nt], acc[mt][nt], 0, 0, 0);
    __syncthreads();
  }

#pragma unroll
  for (int nt = 0; nt < 4; nt++) {
    float bv = bias[n0 + wn + nt * 16 + l16];
#pragma unroll
    for (int mt = 0; mt < 4; mt++)
#pragma unroll
      for (int r = 0; r < 4; r++)
        Ts[wave][(nt * 16 + l16) * 72 + mt * 16 + quad * 4 + r] = f2bf(acc[mt][nt][r] + bv);
  }
  {
    const int R0 = m0 + wm;
    const int b  = R0 >> 11;
    const int key0 = R0 & 2047;
    const int col = n0 + wn + lane;
    const int h  = col >> 6, dv = col & 63;
    const size_t vtrow = ((size_t)(b * 16 + h)) * 64 + dv;
#pragma unroll
    for (int jb = 0; jb < 8; jb++)
      cp16((unsigned short*)&vt[vtrow * 2048 + key0 + jb * 8],
           &Ts[wave][lane * 72 + jb * 8]);
  }
}

// ---------------------------------------------------------------- attention
// One WAVE (64-thread block) per 16 q-rows of one (b,h); grid 2048,
// bh = bid & 63 pins each (b,h)'s K/V slice to one XCD's L2.
// amdgpu_waves_per_eu(2,2): the grid gives exactly 2 waves/EU, so cap the
// scheduler's occupancy target there -> VGPR budget ~256 -> the batched
// K/V loads stay live in registers (deep MLP) instead of being sunk to uses.
__global__ __launch_bounds__(64)
__attribute__((amdgpu_waves_per_eu(2, 2)))
void attn_kernel(
    const unsigned short* __restrict__ qp,   // [B*512, 1024] bf16
    const unsigned short* __restrict__ kp,   // [B*2048, 1024] bf16
    const unsigned short* __restrict__ vt,   // [B*16*64, 2048] bf16 (dv-major)
    const int* __restrict__ mask,            // [B, 2048]
    unsigned short* __restrict__ attn)       // [B*512, 1024] bf16
{
  __shared__ unsigned short Ps[16 * 136];    // P C->A layout round trip

  const int lane = threadIdx.x;
  const int quad = lane >> 4;
  const int l16  = lane & 15;
  const int bid  = blockIdx.x;
  const int bh = bid & 63;       // XCD = bid%8 = bh%8
  const int qg = bid >> 6;       // q-group 0..31
  const int b = bh >> 4, h = bh & 15;

  bf16x8 aq[2];
  {
    const size_t qbase = ((size_t)(b * 512 + qg * 16 + l16)) * 1024 + h * 64;
#pragma unroll
    for (int kc = 0; kc < 2; kc++)
      aq[kc] = ld_frag(&qp[qbase + kc * 32 + quad * 8]);
  }

  const f32x4 fz = {0.0f, 0.0f, 0.0f, 0.0f};
  float m_i[4], l_i[4];
  f32x4 O[4];
#pragma unroll
  for (int r = 0; r < 4; r++) { m_i[r] = -1e30f; l_i[r] = 0.0f; }
#pragma unroll
  for (int d = 0; d < 4; d++) O[d] = fz;

  const size_t kbase = ((size_t)(b * 2048)) * 1024 + h * 64;
  const size_t vbase = ((size_t)(bh * 64)) * 2048;

  for (int kt = 0; kt < 16; kt++) {          // 128 keys per tile
    // ---- BATCH: all 16 K-fragments + 8 mask words
    bf16x8 bk[8][2];
    int mk[8];
#pragma unroll
    for (int nt = 0; nt < 8; nt++) {
      const size_t krow = kbase + ((size_t)(kt * 128 + nt * 16 + l16)) * 1024;
#pragma unroll
      for (int kc = 0; kc < 2; kc++)
        bk[nt][kc] = ld_frag(&kp[krow + kc * 32 + quad * 8]);
      mk[nt] = mask[b * 2048 + kt * 128 + nt * 16 + l16];
    }
    // ---- S = Q K^T (16 x 128)
    f32x4 s[8];
#pragma unroll
    for (int nt = 0; nt < 8; nt++) s[nt] = fz;
#pragma unroll
    for (int nt = 0; nt < 8; nt++)
#pragma unroll
      for (int kc = 0; kc < 2; kc++)
        s[nt] = __builtin_amdgcn_mfma_f32_16x16x32_bf16(aq[kc], bk[nt][kc], s[nt], 0, 0, 0);

    // ---- BATCH: all 16 V-fragments (independent of softmax; latency hidden)
    bf16x8 bv[4][4];
#pragma unroll
    for (int dvt = 0; dvt < 4; dvt++) {
      const size_t vrow = vbase + ((size_t)(dvt * 16 + l16)) * 2048 + kt * 128;
#pragma unroll
      for (int kc = 0; kc < 4; kc++)
        bv[dvt][kc] = ld_frag(&vt[vrow + kc * 32 + quad * 8]);
    }

    // ---- mask + scale
    bool okm[8];
#pragma unroll
    for (int nt = 0; nt < 8; nt++) {
      okm[nt] = (mk[nt] != 0);
#pragma unroll
      for (int r = 0; r < 4; r++)
        s[nt][r] = okm[nt] ? s[nt][r] * 0.125f : -1e30f;
    }
    // ---- online softmax
    float mnew[4];
#pragma unroll
    for (int r = 0; r < 4; r++) {
      float mx = s[0][r];
#pragma unroll
      for (int nt = 1; nt < 8; nt++) mx = fmaxf(mx, s[nt][r]);
      mnew[r] = mx;
    }
#pragma unroll
    for (int off = 1; off < 16; off <<= 1)
#pragma unroll
      for (int r = 0; r < 4; r++) mnew[r] = fmaxf(mnew[r], __shfl_xor(mnew[r], off));
#pragma unroll
    for (int r = 0; r < 4; r++) mnew[r] = fmaxf(mnew[r], m_i[r]);

    float alpha[4], rs[4];
#pragma unroll
    for (int r = 0; r < 4; r++) {
      alpha[r] = __expf(m_i[r] - mnew[r]);
      m_i[r] = mnew[r];
      rs[r] = 0.0f;
    }
#pragma unroll
    for (int nt = 0; nt < 8; nt++)
#pragma unroll
      for (int r = 0; r < 4; r++) {
        float p = okm[nt] ? __expf(s[nt][r] - mnew[r]) : 0.0f;
        rs[r] += p;
        Ps[(quad * 4 + r) * 136 + nt * 16 + l16] = f2bf(p);
      }
#pragma unroll
    for (int off = 1; off < 16; off <<= 1)
#pragma unroll
      for (int r = 0; r < 4; r++) rs[r] += __shfl_xor(rs[r], off);
#pragma unroll
    for (int r = 0; r < 4; r++) l_i[r] = l_i[r] * alpha[r] + rs[r];
#pragma unroll
    for (int d = 0; d < 4; d++)
#pragma unroll
      for (int r = 0; r < 4; r++) O[d][r] = O[d][r] * alpha[r];

    // ---- O += P V  (P A-frags from wave-private LDS; V already in regs)
    bf16x8 ap[4];
#pragma unroll
    for (int kc = 0; kc < 4; kc++)
      ap[kc] = ld_frag(&Ps[l16 * 136 + kc * 32 + quad * 8]);
#pragma unroll
    for (int dvt = 0; dvt < 4; dvt++)
#pragma unroll
      for (int kc = 0; kc < 4; kc++)
        O[dvt] = __builtin_amdgcn_mfma_f32_16x16x32_bf16(ap[kc], bv[dvt][kc], O[dvt], 0, 0, 0);
  }

#pragma unroll
  for (int r = 0; r < 4; r++) {
    float linv = (l_i[r] > 0.0f) ? (1.0f / l_i[r]) : 0.0f;
    int row = b * 512 + qg * 16 + quad * 4 + r;
#pragma unroll
    for (int dvt = 0; dvt < 4; dvt++)
      attn[(size_t)row * 1024 + h * 64 + dvt * 16 + l16] = f2bf(O[dvt][r] * linv);
  }
}

// ---------------------------------------------------------------- layernorm
__global__ __launch_bounds__(256) void ln_kernel(
    const unsigned short* __restrict__ x,
    const float* __restrict__ resid,
    const float* __restrict__ gamma,
    const float* __restrict__ beta,
    float* __restrict__ out)
{
  const int row = blockIdx.x;
  const int t = threadIdx.x;
  const int wave = t >> 6, lane = t & 63;
  __shared__ float red[8];
  float v[4];
  float s1 = 0.0f, s2 = 0.0f;
#pragma unroll
  for (int i = 0; i < 4; i++) {
    int e = t + i * 256;
    float val = bf2f(x[(size_t)row * 1024 + e]) + resid[(size_t)row * 1024 + e];
    v[i] = val; s1 += val; s2 += val * val;
  }
#pragma unroll
  for (int off = 1; off < 64; off <<= 1) { s1 += __shfl_xor(s1, off); s2 += __shfl_xor(s2, off); }
  if (lane == 0) { red[wave] = s1; red[4 + wave] = s2; }
  __syncthreads();
  s1 = red[0] + red[1] + red[2] + red[3];
  s2 = red[4] + red[5] + red[6] + red[7];
  float mu  = s1 * (1.0f / 1024.0f);
  float var = s2 * (1.0f / 1024.0f) - mu * mu;
  float rstd = rsqrtf(var + 1e-5f);
#pragma unroll
  for (int i = 0; i < 4; i++) {
    int e = t + i * 256;
    out[(size_t)row * 1024 + e] = (v[i] - mu) * rstd * gamma[e] + beta[e];
  }
}

// ---------------------------------------------------------------- launch
extern "C" void kernel_launch(void* const* d_in, const int* in_sizes, int n_in,
                              void* d_out, int out_size, void* d_ws, size_t ws_size,
                              hipStream_t stream) {
  (void)out_size;
  const float* Q = (const float*)d_in[0];
  const float* K = (const float*)d_in[1];
  const float* V = (const float*)d_in[2];

  int ix = 3;
  if (ix < n_in && in_sizes[ix] == 1) ix++;   // skip node_num scalar if passed
  const int* mask  = (const int*)d_in[ix++];
  const float* Wq = (const float*)d_in[ix++]; const float* bq = (const float*)d_in[ix++];
  const float* Wk = (const float*)d_in[ix++]; const float* bk = (const float*)d_in[ix++];
  const float* Wv = (const float*)d_in[ix++]; const float* bv = (const float*)d_in[ix++];
  const float* Wo = (const float*)d_in[ix++]; const float* bo = (const float*)d_in[ix++];
  const float* gm = (const float*)d_in[ix++]; const float* bt = (const float*)d_in[ix++];

  char* ws = (char*)d_ws;
  dim3 blk(256);

  if (ws_size >= (64ull << 20)) {
    // ---- fast path (64 MB):
    // WT4 8 | qp 4 | kp 16 | vt 16 | at 4 (alias Qb) | KVb 16
    unsigned short* WT4 = (unsigned short*)(ws);                  // 4 x 1M elems
    unsigned short* qp  = (unsigned short*)(ws + (8ull  << 20));  // reused as op
    unsigned short* kp  = (unsigned short*)(ws + (12ull << 20));
    unsigned short* vt  = (unsigned short*)(ws + (28ull << 20));
    unsigned short* at  = (unsigned short*)(ws + (44ull << 20));
    unsigned short* qb  = at;                                     // dead before attn
    unsigned short* kvb = (unsigned short*)(ws + (48ull << 20));

    cvt_kernel<<<dim3(1024), blk, 0, stream>>>(Q, qb, 262144);
    cvt_kernel<<<dim3(4096), blk, 0, stream>>>(K, kvb, 1048576);
    transpose4_kernel<<<dim3(16, 16, 4), blk, 0, stream>>>(Wq, Wk, Wv, Wo, WT4);

    gemm_bt_kernel<<<dim3(16, 8), blk, 0, stream>>>(qb, WT4, bq, qp, 2048, 1024, 1024, 0);
    gemm_bt_kernel<<<dim3(64, 8), blk, 0, stream>>>(kvb, WT4 + 1048576, bk, kp, 8192, 1024, 1024, 0);
    cvt_kernel<<<dim3(4096), blk, 0, stream>>>(V, kvb, 1048576);   // kvb dead after k-proj
    gemm_bt_vt_kernel<<<dim3(64, 8), blk, 0, stream>>>(kvb, WT4 + 2097152, bv, vt, 0);

    attn_kernel<<<dim3(2048), dim3(64), 0, stream>>>(qp, kp, vt, mask, at);

    gemm_bt_kernel<<<dim3(16, 8), blk, 0, stream>>>(at, WT4 + 3145728, bo, qp, 2048, 1024, 1024, 0);
    ln_kernel<<<dim3(2048), blk, 0, stream>>>(qp, Q, gm, bt, (float*)d_out);
  } else {
    // ---- fallback path (42 MB, R7 sequence)
    unsigned short* WT = (unsigned short*)(ws);
    unsigned short* qp = (unsigned short*)(ws + (2ull  << 20));
    unsigned short* kp = (unsigned short*)(ws + (6ull  << 20));
    unsigned short* vt = (unsigned short*)(ws + (22ull << 20));
    unsigned short* at = (unsigned short*)(ws + (38ull << 20));
    unsigned short* op = qp;

    transpose_kernel<<<dim3(16, 16), blk, 0, stream>>>(Wq, WT, 1024);
    gemm_bt_kernel<<<dim3(16, 8), blk, 0, stream>>>(Q, WT, bq, qp, 2048, 1024, 1024, 1);
    transpose_kernel<<<dim3(16, 16), blk, 0, stream>>>(Wk, WT, 1024);
    gemm_bt_kernel<<<dim3(64, 8), blk, 0, stream>>>(K, WT, bk, kp, 8192, 1024, 1024, 1);
    transpose_kernel<<<dim3(16, 16), blk, 0, stream>>>(Wv, WT, 1024);
    gemm_bt_vt_kernel<<<dim3(64, 8), blk, 0, stream>>>(V, WT, bv, vt, 1);

    attn_kernel<<<dim3(2048), dim3(64), 0, stream>>>(qp, kp, vt, mask, at);

    transpose_kernel<<<dim3(16, 16), blk, 0, stream>>>(Wo, WT, 1024);
    gemm_bt_kernel<<<dim3(16, 8), blk, 0, stream>>>(at, WT, bo, op, 2048, 1024, 1024, 0);

    ln_kernel<<<dim3(2048), blk, 0, stream>>>(op, Q, gm, bt, (float*)d_out);
  }
}